// Round 2
// baseline (13402.966 us; speedup 1.0000x reference)
//
#include <hip/hip_runtime.h>

#define B_ 512
#define T_ 256
#define D_ 128
#define H_ 512

typedef __bf16 bf16x8 __attribute__((ext_vector_type(8)));
typedef float f32x4 __attribute__((ext_vector_type(4)));

__device__ __forceinline__ float sigm(float x) { return 1.f / (1.f + __expf(-x)); }
__device__ __forceinline__ float tanh_(float x) { return 2.f / (1.f + __expf(-2.f * x)) - 1.f; }

__device__ __forceinline__ void split2(float v, __bf16& hi, __bf16& lo) {
    hi = (__bf16)v;
    lo = (__bf16)(v - (float)hi);
}

// ---------------- weight convert: fp32 -> split bf16 (hi+lo), transposed to [N][K] ----------------
__global__ void k_convert(const float* __restrict__ k0, const float* __restrict__ r0,
                          const float* __restrict__ k1, const float* __restrict__ r1,
                          const float* __restrict__ W,
                          __bf16* __restrict__ wB0Th, __bf16* __restrict__ wB0Tl,  // [2048][640]
                          __bf16* __restrict__ wB1Th, __bf16* __restrict__ wB1Tl,  // [2048][1024]
                          __bf16* __restrict__ wWTh,  __bf16* __restrict__ wWTl)   // [128][512]
{
    int tid = blockIdx.x * blockDim.x + threadIdx.x;
    int nth = gridDim.x * blockDim.x;
    for (int idx = tid; idx < 640 * 2048; idx += nth) {
        int k = idx >> 11, n = idx & 2047;
        float v = (k < 128) ? k0[k * 2048 + n] : r0[(k - 128) * 2048 + n];
        split2(v, wB0Th[n * 640 + k], wB0Tl[n * 640 + k]);
    }
    for (int idx = tid; idx < 1024 * 2048; idx += nth) {
        int k = idx >> 11, n = idx & 2047;
        float v = (k < 512) ? k1[k * 2048 + n] : r1[(k - 512) * 2048 + n];
        split2(v, wB1Th[n * 1024 + k], wB1Tl[n * 1024 + k]);
    }
    for (int idx = tid; idx < 512 * 128; idx += nth) {
        int k = idx >> 7, n = idx & 127;
        split2(W[k * 128 + n], wWTh[n * 512 + k], wWTl[n * 512 + k]);
    }
}

// ---------------- init: cur = x[:,0,:] (split), zero h/c state ----------------
__global__ void k_init(const float* __restrict__ x,
                       __bf16* __restrict__ curh, __bf16* __restrict__ curl,
                       __bf16* __restrict__ h0ah, __bf16* __restrict__ h0al,
                       __bf16* __restrict__ h0bh, __bf16* __restrict__ h0bl,
                       __bf16* __restrict__ h1ah, __bf16* __restrict__ h1al,
                       __bf16* __restrict__ h1bh, __bf16* __restrict__ h1bl,
                       float* __restrict__ c0, float* __restrict__ c1)
{
    int tid = blockIdx.x * blockDim.x + threadIdx.x;
    int nth = gridDim.x * blockDim.x;
    for (int idx = tid; idx < B_ * D_; idx += nth) {
        int b = idx >> 7, d = idx & 127;
        split2(x[b * (T_ * D_) + d], curh[idx], curl[idx]);  // t=0: missing stays 128.0 exactly
    }
    for (int idx = tid; idx < B_ * H_; idx += nth) {
        h0ah[idx] = (__bf16)0.f; h0al[idx] = (__bf16)0.f;
        h0bh[idx] = (__bf16)0.f; h0bl[idx] = (__bf16)0.f;
        h1ah[idx] = (__bf16)0.f; h1al[idx] = (__bf16)0.f;
        h1bh[idx] = (__bf16)0.f; h1bl[idx] = (__bf16)0.f;
        c0[idx] = 0.f; c1[idx] = 0.f;
    }
}

// ---------------- one LSTM layer step, split-precision GEMM ----------------
// z = A@B^T + bias -> gates -> h,c.  A split into [A1 | A2] K-segments, each as hi/lo pair.
// BT is [2048][KTOT] bf16 hi/lo.  Product: Ahi*Bhi + Ahi*Blo + Alo*Bhi (fp32-quality).
// Grid: (32 j-tiles of 16 h-cols, 8 m-tiles of 64 rows). 256 threads = 4 waves.
template <int KTOT, int K1>
__global__ __launch_bounds__(256) void k_layer(
    const __bf16* __restrict__ A1h, const __bf16* __restrict__ A1l, int lda1,
    const __bf16* __restrict__ A2h, const __bf16* __restrict__ A2l, int lda2,
    const __bf16* __restrict__ BTh, const __bf16* __restrict__ BTl,
    const float* __restrict__ bias,       // [2048] gate order i,f,g,o
    float* __restrict__ cstate,           // [512][512] fp32, read-modify-write
    __bf16* __restrict__ houth,           // [512][512] bf16 hi
    __bf16* __restrict__ houtl,           //            bf16 lo
    float* __restrict__ hout_f32)         // optional fp32 copy (last_cell)
{
    __shared__ __align__(16) __bf16 Alds[2][64 * 40];       // hi/lo: 64 rows x 32 k (pad 40)
    __shared__ __align__(16) __bf16 Blds[2][4 * 16 * 40];   // hi/lo: 4 gates x 16 cols x 32 k

    const int j0 = blockIdx.x * 16;
    const int m0 = blockIdx.y * 64;
    const int tid = threadIdx.x;
    const int w = tid >> 6, l = tid & 63;

    const int arow = tid >> 2;           // 0..63
    const int akc = (tid & 3) << 3;      // 0,8,16,24
    const int bg = tid >> 6;             // gate 0..3
    const int bcol = (tid >> 2) & 15;    // 0..15
    const int bkc = (tid & 3) << 3;

    f32x4 acc[4] = {};

    for (int kb = 0; kb < KTOT; kb += 32) {
        size_t aoff = (kb < K1) ? ((size_t)(m0 + arow) * lda1 + kb + akc)
                                : ((size_t)(m0 + arow) * lda2 + (kb - K1) + akc);
        const __bf16* ah = (kb < K1) ? A1h : A2h;
        const __bf16* al = (kb < K1) ? A1l : A2l;
        *reinterpret_cast<uint4*>(&Alds[0][arow * 40 + akc]) =
            *reinterpret_cast<const uint4*>(ah + aoff);
        *reinterpret_cast<uint4*>(&Alds[1][arow * 40 + akc]) =
            *reinterpret_cast<const uint4*>(al + aoff);
        size_t boff = (size_t)(bg * 512 + j0 + bcol) * KTOT + kb + bkc;
        *reinterpret_cast<uint4*>(&Blds[0][(bg * 16 + bcol) * 40 + bkc]) =
            *reinterpret_cast<const uint4*>(BTh + boff);
        *reinterpret_cast<uint4*>(&Blds[1][(bg * 16 + bcol) * 40 + bkc]) =
            *reinterpret_cast<const uint4*>(BTl + boff);
        __syncthreads();

        int aidx = (w * 16 + (l & 15)) * 40 + ((l >> 4) << 3);
        bf16x8 ah8 = *reinterpret_cast<const bf16x8*>(&Alds[0][aidx]);
        bf16x8 al8 = *reinterpret_cast<const bf16x8*>(&Alds[1][aidx]);
#pragma unroll
        for (int g = 0; g < 4; ++g) {
            int bidx = (g * 16 + (l & 15)) * 40 + ((l >> 4) << 3);
            bf16x8 bh8 = *reinterpret_cast<const bf16x8*>(&Blds[0][bidx]);
            bf16x8 bl8 = *reinterpret_cast<const bf16x8*>(&Blds[1][bidx]);
            acc[g] = __builtin_amdgcn_mfma_f32_16x16x32_bf16(ah8, bh8, acc[g], 0, 0, 0);
            acc[g] = __builtin_amdgcn_mfma_f32_16x16x32_bf16(ah8, bl8, acc[g], 0, 0, 0);
            acc[g] = __builtin_amdgcn_mfma_f32_16x16x32_bf16(al8, bh8, acc[g], 0, 0, 0);
        }
        __syncthreads();
    }

    const int col = j0 + (l & 15);
#pragma unroll
    for (int r = 0; r < 4; ++r) {
        int row = m0 + w * 16 + ((l >> 4) << 2) + r;
        float zi = acc[0][r] + bias[col];
        float zf = acc[1][r] + bias[512 + col];
        float zg = acc[2][r] + bias[1024 + col];
        float zo = acc[3][r] + bias[1536 + col];
        float gi = sigm(zi), gf = sigm(zf), gg = tanh_(zg), go = sigm(zo);
        int cidx = row * H_ + col;
        float c = gf * cstate[cidx] + gi * gg;
        cstate[cidx] = c;
        float h = go * tanh_(c);
        split2(h, houth[cidx], houtl[cidx]);
        if (hout_f32) hout_f32[cidx] = h;
    }
}

// ---------------- pred = h1_prev @ W^T + b_out; impute cur; store pred to d_out ----------------
// Grid: (4 j-tiles of 32 cols, 8 m-tiles of 64 rows), 256 threads = 4 waves.
__global__ __launch_bounds__(256) void k_pred(
    const __bf16* __restrict__ h1ph, const __bf16* __restrict__ h1pl,  // [512][512]
    const __bf16* __restrict__ WTh, const __bf16* __restrict__ WTl,    // [128][512]
    const float* __restrict__ bout,      // [128]
    const float* __restrict__ x,         // [512][256][128]
    int t,
    __bf16* __restrict__ curh, __bf16* __restrict__ curl,  // [512][128]
    float* __restrict__ outPred)         // [B*(T-1)][128] region of d_out
{
    __shared__ __align__(16) __bf16 Alds[2][64 * 40];
    __shared__ __align__(16) __bf16 Blds[2][32 * 40];

    const int j0 = blockIdx.x * 32;
    const int m0 = blockIdx.y * 64;
    const int tid = threadIdx.x;
    const int w = tid >> 6, l = tid & 63;
    const int arow = tid >> 2, akc = (tid & 3) << 3;

    f32x4 acc[2] = {};

    for (int kb = 0; kb < 512; kb += 32) {
        size_t aoff = (size_t)(m0 + arow) * H_ + kb + akc;
        *reinterpret_cast<uint4*>(&Alds[0][arow * 40 + akc]) =
            *reinterpret_cast<const uint4*>(h1ph + aoff);
        *reinterpret_cast<uint4*>(&Alds[1][arow * 40 + akc]) =
            *reinterpret_cast<const uint4*>(h1pl + aoff);
        if (tid < 128) {
            int bc = tid >> 2, bk = (tid & 3) << 3;
            size_t boff = (size_t)(j0 + bc) * 512 + kb + bk;
            *reinterpret_cast<uint4*>(&Blds[0][bc * 40 + bk]) =
                *reinterpret_cast<const uint4*>(WTh + boff);
            *reinterpret_cast<uint4*>(&Blds[1][bc * 40 + bk]) =
                *reinterpret_cast<const uint4*>(WTl + boff);
        }
        __syncthreads();
        int aidx = (w * 16 + (l & 15)) * 40 + ((l >> 4) << 3);
        bf16x8 ah8 = *reinterpret_cast<const bf16x8*>(&Alds[0][aidx]);
        bf16x8 al8 = *reinterpret_cast<const bf16x8*>(&Alds[1][aidx]);
#pragma unroll
        for (int s = 0; s < 2; ++s) {
            int bidx = (s * 16 + (l & 15)) * 40 + ((l >> 4) << 3);
            bf16x8 bh8 = *reinterpret_cast<const bf16x8*>(&Blds[0][bidx]);
            bf16x8 bl8 = *reinterpret_cast<const bf16x8*>(&Blds[1][bidx]);
            acc[s] = __builtin_amdgcn_mfma_f32_16x16x32_bf16(ah8, bh8, acc[s], 0, 0, 0);
            acc[s] = __builtin_amdgcn_mfma_f32_16x16x32_bf16(ah8, bl8, acc[s], 0, 0, 0);
            acc[s] = __builtin_amdgcn_mfma_f32_16x16x32_bf16(al8, bh8, acc[s], 0, 0, 0);
        }
        __syncthreads();
    }

#pragma unroll
    for (int s = 0; s < 2; ++s) {
        int col = j0 + s * 16 + (l & 15);
#pragma unroll
        for (int r = 0; r < 4; ++r) {
            int b = m0 + w * 16 + ((l >> 4) << 2) + r;
            float pred = acc[s][r] + bout[col];
            float xv = x[(b * T_ + t) * D_ + col];
            float cv = (xv == 128.0f) ? pred : xv;
            int ci = b * D_ + col;
            split2(cv, curh[ci], curl[ci]);
            outPred[((size_t)b * (T_ - 1) + (t - 1)) * D_ + col] = pred;
        }
    }
}

extern "C" void kernel_launch(void* const* d_in, const int* in_sizes, int n_in,
                              void* d_out, int out_size, void* d_ws, size_t ws_size,
                              hipStream_t stream)
{
    const float* x  = (const float*)d_in[0];
    const float* k0 = (const float*)d_in[1];
    const float* r0 = (const float*)d_in[2];
    const float* b0 = (const float*)d_in[3];
    const float* k1 = (const float*)d_in[4];
    const float* r1 = (const float*)d_in[5];
    const float* b1 = (const float*)d_in[6];
    const float* W  = (const float*)d_in[7];
    const float* bo = (const float*)d_in[8];
    float* out = (float*)d_out;

    char* ws = (char*)d_ws;
    size_t off = 0;
    auto alloc = [&](size_t bytes) { void* p = ws + off; off += (bytes + 255) & ~255ull; return p; };
    __bf16* wB0Th = (__bf16*)alloc((size_t)2048 * 640 * 2);
    __bf16* wB0Tl = (__bf16*)alloc((size_t)2048 * 640 * 2);
    __bf16* wB1Th = (__bf16*)alloc((size_t)2048 * 1024 * 2);
    __bf16* wB1Tl = (__bf16*)alloc((size_t)2048 * 1024 * 2);
    __bf16* wWTh  = (__bf16*)alloc((size_t)128 * 512 * 2);
    __bf16* wWTl  = (__bf16*)alloc((size_t)128 * 512 * 2);
    __bf16* curh  = (__bf16*)alloc((size_t)B_ * D_ * 2);
    __bf16* curl  = (__bf16*)alloc((size_t)B_ * D_ * 2);
    __bf16* h0h[2] = { (__bf16*)alloc((size_t)B_ * H_ * 2), (__bf16*)alloc((size_t)B_ * H_ * 2) };
    __bf16* h0l[2] = { (__bf16*)alloc((size_t)B_ * H_ * 2), (__bf16*)alloc((size_t)B_ * H_ * 2) };
    __bf16* h1h[2] = { (__bf16*)alloc((size_t)B_ * H_ * 2), (__bf16*)alloc((size_t)B_ * H_ * 2) };
    __bf16* h1l[2] = { (__bf16*)alloc((size_t)B_ * H_ * 2), (__bf16*)alloc((size_t)B_ * H_ * 2) };
    float* c0 = (float*)alloc((size_t)B_ * H_ * 4);
    float* c1 = (float*)alloc((size_t)B_ * H_ * 4);

    k_convert<<<2048, 256, 0, stream>>>(k0, r0, k1, r1, W, wB0Th, wB0Tl, wB1Th, wB1Tl, wWTh, wWTl);
    k_init<<<1024, 256, 0, stream>>>(x, curh, curl,
                                     h0h[0], h0l[0], h0h[1], h0l[1],
                                     h1h[0], h1l[0], h1h[1], h1l[1], c0, c1);

    float* lastcell = out + (size_t)B_ * (T_ - 1) * D_;

    for (int t = 0; t < T_; ++t) {
        int cu = t & 1, pv = cu ^ 1;
        if (t > 0)
            k_pred<<<dim3(4, 8), 256, 0, stream>>>(h1h[pv], h1l[pv], wWTh, wWTl, bo, x, t,
                                                   curh, curl, out);
        k_layer<640, 128><<<dim3(32, 8), 256, 0, stream>>>(
            curh, curl, D_, h0h[pv], h0l[pv], H_, wB0Th, wB0Tl, b0, c0,
            h0h[cu], h0l[cu], nullptr);
        k_layer<1024, 512><<<dim3(32, 8), 256, 0, stream>>>(
            h0h[cu], h0l[cu], H_, h1h[pv], h1l[pv], H_, wB1Th, wB1Tl, b1, c1,
            h1h[cu], h1l[cu], (t == T_ - 1) ? lastcell : nullptr);
    }
}

// Round 3
// 8120.947 us; speedup vs baseline: 1.6504x; 1.6504x over previous
//
#include <hip/hip_runtime.h>

#define B_ 512
#define T_ 256
#define D_ 128
#define H_ 512

typedef __bf16 bf16x8 __attribute__((ext_vector_type(8)));
typedef float f32x4 __attribute__((ext_vector_type(4)));

__device__ __forceinline__ float sigm(float x) { return 1.f / (1.f + __expf(-x)); }
__device__ __forceinline__ float tanh_(float x) { return 2.f / (1.f + __expf(-2.f * x)) - 1.f; }

__device__ __forceinline__ void split2(float v, __bf16& hi, __bf16& lo) {
    hi = (__bf16)v;
    lo = (__bf16)(v - (float)hi);
}

// ---------------- weight convert: fp32 -> split bf16 (hi+lo), transposed to [N][K] ----------------
__global__ void k_convert(const float* __restrict__ k0, const float* __restrict__ r0,
                          const float* __restrict__ k1, const float* __restrict__ r1,
                          const float* __restrict__ W,
                          __bf16* __restrict__ wB0Th, __bf16* __restrict__ wB0Tl,  // [2048][640]
                          __bf16* __restrict__ wB1Th, __bf16* __restrict__ wB1Tl,  // [2048][1024]
                          __bf16* __restrict__ wWTh,  __bf16* __restrict__ wWTl)   // [128][512]
{
    int tid = blockIdx.x * blockDim.x + threadIdx.x;
    int nth = gridDim.x * blockDim.x;
    for (int idx = tid; idx < 640 * 2048; idx += nth) {
        int k = idx >> 11, n = idx & 2047;
        float v = (k < 128) ? k0[k * 2048 + n] : r0[(k - 128) * 2048 + n];
        split2(v, wB0Th[n * 640 + k], wB0Tl[n * 640 + k]);
    }
    for (int idx = tid; idx < 1024 * 2048; idx += nth) {
        int k = idx >> 11, n = idx & 2047;
        float v = (k < 512) ? k1[k * 2048 + n] : r1[(k - 512) * 2048 + n];
        split2(v, wB1Th[n * 1024 + k], wB1Tl[n * 1024 + k]);
    }
    for (int idx = tid; idx < 512 * 128; idx += nth) {
        int k = idx >> 7, n = idx & 127;
        split2(W[k * 128 + n], wWTh[n * 512 + k], wWTl[n * 512 + k]);
    }
}

// ---------------- init: cur = x[:,0,:] (split), zero h/c state ----------------
__global__ void k_init(const float* __restrict__ x,
                       __bf16* __restrict__ curh, __bf16* __restrict__ curl,
                       __bf16* __restrict__ h0ah, __bf16* __restrict__ h0al,
                       __bf16* __restrict__ h0bh, __bf16* __restrict__ h0bl,
                       __bf16* __restrict__ h1ah, __bf16* __restrict__ h1al,
                       __bf16* __restrict__ h1bh, __bf16* __restrict__ h1bl,
                       float* __restrict__ c0, float* __restrict__ c1)
{
    int tid = blockIdx.x * blockDim.x + threadIdx.x;
    int nth = gridDim.x * blockDim.x;
    for (int idx = tid; idx < B_ * D_; idx += nth) {
        int b = idx >> 7, d = idx & 127;
        split2(x[b * (T_ * D_) + d], curh[idx], curl[idx]);  // t=0: missing stays 128.0 exactly
    }
    for (int idx = tid; idx < B_ * H_; idx += nth) {
        h0ah[idx] = (__bf16)0.f; h0al[idx] = (__bf16)0.f;
        h0bh[idx] = (__bf16)0.f; h0bl[idx] = (__bf16)0.f;
        h1ah[idx] = (__bf16)0.f; h1al[idx] = (__bf16)0.f;
        h1bh[idx] = (__bf16)0.f; h1bl[idx] = (__bf16)0.f;
        c0[idx] = 0.f; c1[idx] = 0.f;
    }
}

// ---------------- one LSTM layer step, split-precision GEMM, prefetch + K-split waves ----
// z = A@B^T + bias -> gates -> h,c.  A = [A1 | A2] K-segments, hi/lo pairs.
// BT is [2048][KTOT] hi/lo.  Product: Ahi*Bhi + Ahi*Blo + Alo*Bhi.
// Grid (32 j-tiles of 16 cols, 8 m-tiles of 64 rows), 512 threads = 8 waves.
// Wave w: rows wpair*16.. (wpair=w>>1), K-half ksub=w&1. K-step 64/iter.
template <int KTOT, int K1>
__global__ __launch_bounds__(512) void k_layer(
    const __bf16* __restrict__ A1h, const __bf16* __restrict__ A1l, int lda1,
    const __bf16* __restrict__ A2h, const __bf16* __restrict__ A2l, int lda2,
    const __bf16* __restrict__ BTh, const __bf16* __restrict__ BTl,
    const float* __restrict__ bias,       // [2048] gate order i,f,g,o
    float* __restrict__ cstate,           // [512][512] fp32 rmw
    __bf16* __restrict__ houth, __bf16* __restrict__ houtl,
    float* __restrict__ hout_f32)         // optional fp32 copy (last_cell)
{
    constexpr int LSTR = 72;              // 64 k + pad (144B rows: 2-way banks = free)
    __shared__ __align__(16) __bf16 AhL[64 * LSTR], AlL[64 * LSTR];
    __shared__ __align__(16) __bf16 BhL[64 * LSTR], BlL[64 * LSTR];
    __shared__ __align__(16) float zred[4][64][20];

    const int j0 = blockIdx.x * 16;
    const int m0 = blockIdx.y * 64;
    const int tid = threadIdx.x;
    const int lane = tid & 63;
    const int wave = tid >> 6;
    const int wpair = wave >> 1;          // 0..3 -> 16-row group
    const int ksub = wave & 1;            // K-half

    const int srow = tid >> 3;            // staging row 0..63
    const int skc = (tid & 7) << 3;       // staging k 0..56
    const int bgrow = (srow >> 4) * 512 + j0 + (srow & 15);  // BT global row

    uint4 pAh, pAl, pBh, pBl;
    auto loadA = [&](int kb) {
        int k = kb + skc;
        const __bf16 *ah, *al; size_t off;
        if (k < K1) { ah = A1h; al = A1l; off = (size_t)(m0 + srow) * lda1 + k; }
        else        { ah = A2h; al = A2l; off = (size_t)(m0 + srow) * lda2 + (k - K1); }
        pAh = *reinterpret_cast<const uint4*>(ah + off);
        pAl = *reinterpret_cast<const uint4*>(al + off);
    };
    auto loadB = [&](int kb) {
        size_t off = (size_t)bgrow * KTOT + kb + skc;
        pBh = *reinterpret_cast<const uint4*>(BTh + off);
        pBl = *reinterpret_cast<const uint4*>(BTl + off);
    };

    loadA(0); loadB(0);

    f32x4 acc[4] = {};
    const int aidx = (wpair * 16 + (lane & 15)) * LSTR + ksub * 32 + ((lane >> 4) << 3);
    const int kf = ksub * 32 + ((lane >> 4) << 3);

    for (int kb = 0; kb < KTOT; kb += 64) {
        __syncthreads();                  // LDS free
        *reinterpret_cast<uint4*>(&AhL[srow * LSTR + skc]) = pAh;
        *reinterpret_cast<uint4*>(&AlL[srow * LSTR + skc]) = pAl;
        *reinterpret_cast<uint4*>(&BhL[srow * LSTR + skc]) = pBh;
        *reinterpret_cast<uint4*>(&BlL[srow * LSTR + skc]) = pBl;
        if (kb + 64 < KTOT) { loadA(kb + 64); loadB(kb + 64); }  // prefetch next tile
        __syncthreads();                  // LDS ready
        bf16x8 a_h = *reinterpret_cast<const bf16x8*>(&AhL[aidx]);
        bf16x8 a_l = *reinterpret_cast<const bf16x8*>(&AlL[aidx]);
#pragma unroll
        for (int g = 0; g < 4; ++g) {
            int bi = (g * 16 + (lane & 15)) * LSTR + kf;
            bf16x8 b_h = *reinterpret_cast<const bf16x8*>(&BhL[bi]);
            bf16x8 b_l = *reinterpret_cast<const bf16x8*>(&BlL[bi]);
            acc[g] = __builtin_amdgcn_mfma_f32_16x16x32_bf16(a_h, b_h, acc[g], 0, 0, 0);
            acc[g] = __builtin_amdgcn_mfma_f32_16x16x32_bf16(a_h, b_l, acc[g], 0, 0, 0);
            acc[g] = __builtin_amdgcn_mfma_f32_16x16x32_bf16(a_l, b_h, acc[g], 0, 0, 0);
        }
    }

    // cross-K-half reduction: ksub=1 waves park partials in LDS
    if (ksub == 1) {
#pragma unroll
        for (int g = 0; g < 4; ++g)
            *reinterpret_cast<f32x4*>(&zred[wpair][lane][g * 4]) = acc[g];
    }
    __syncthreads();
    if (ksub == 0) {
        const int col = j0 + (lane & 15);
#pragma unroll
        for (int r = 0; r < 4; ++r) {
            int row = m0 + wpair * 16 + ((lane >> 4) << 2) + r;
            float zi = acc[0][r] + zred[wpair][lane][0 + r] + bias[col];
            float zf = acc[1][r] + zred[wpair][lane][4 + r] + bias[512 + col];
            float zg = acc[2][r] + zred[wpair][lane][8 + r] + bias[1024 + col];
            float zo = acc[3][r] + zred[wpair][lane][12 + r] + bias[1536 + col];
            float gi = sigm(zi), gf = sigm(zf), gg = tanh_(zg), go = sigm(zo);
            int cidx = row * H_ + col;
            float c = gf * cstate[cidx] + gi * gg;
            cstate[cidx] = c;
            float h = go * tanh_(c);
            split2(h, houth[cidx], houtl[cidx]);
            if (hout_f32) hout_f32[cidx] = h;
        }
    }
}

// ---------------- pred = h1_prev @ W^T + b_out; impute cur; store pred to d_out ----------------
// Grid: (4 j-tiles of 32 cols, 8 m-tiles of 64 rows), 256 threads, reg-prefetch.
__global__ __launch_bounds__(256) void k_pred(
    const __bf16* __restrict__ h1ph, const __bf16* __restrict__ h1pl,  // [512][512]
    const __bf16* __restrict__ WTh, const __bf16* __restrict__ WTl,    // [128][512]
    const float* __restrict__ bout,
    const float* __restrict__ x,         // [512][256][128]
    int t,
    __bf16* __restrict__ curh, __bf16* __restrict__ curl,  // [512][128]
    float* __restrict__ outPred)         // [B*(T-1)][128] region of d_out
{
    __shared__ __align__(16) __bf16 Alds[2][64 * 40];
    __shared__ __align__(16) __bf16 Blds[2][32 * 40];

    const int j0 = blockIdx.x * 32;
    const int m0 = blockIdx.y * 64;
    const int tid = threadIdx.x;
    const int w = tid >> 6, l = tid & 63;
    const int arow = tid >> 2, akc = (tid & 3) << 3;
    const int bc = (tid >> 2) & 31, bk = (tid & 3) << 3;

    uint4 pAh, pAl, pBh, pBl;
    auto loadA = [&](int kb) {
        size_t off = (size_t)(m0 + arow) * H_ + kb + akc;
        pAh = *reinterpret_cast<const uint4*>(h1ph + off);
        pAl = *reinterpret_cast<const uint4*>(h1pl + off);
    };
    auto loadB = [&](int kb) {
        if (tid < 128) {
            size_t off = (size_t)(j0 + bc) * 512 + kb + bk;
            pBh = *reinterpret_cast<const uint4*>(WTh + off);
            pBl = *reinterpret_cast<const uint4*>(WTl + off);
        }
    };
    loadA(0); loadB(0);

    f32x4 acc[2] = {};

    for (int kb = 0; kb < 512; kb += 32) {
        __syncthreads();
        *reinterpret_cast<uint4*>(&Alds[0][arow * 40 + akc]) = pAh;
        *reinterpret_cast<uint4*>(&Alds[1][arow * 40 + akc]) = pAl;
        if (tid < 128) {
            *reinterpret_cast<uint4*>(&Blds[0][bc * 40 + bk]) = pBh;
            *reinterpret_cast<uint4*>(&Blds[1][bc * 40 + bk]) = pBl;
        }
        if (kb + 32 < 512) { loadA(kb + 32); loadB(kb + 32); }
        __syncthreads();
        int aidx = (w * 16 + (l & 15)) * 40 + ((l >> 4) << 3);
        bf16x8 ah8 = *reinterpret_cast<const bf16x8*>(&Alds[0][aidx]);
        bf16x8 al8 = *reinterpret_cast<const bf16x8*>(&Alds[1][aidx]);
#pragma unroll
        for (int s = 0; s < 2; ++s) {
            int bidx = (s * 16 + (l & 15)) * 40 + ((l >> 4) << 3);
            bf16x8 bh8 = *reinterpret_cast<const bf16x8*>(&Blds[0][bidx]);
            bf16x8 bl8 = *reinterpret_cast<const bf16x8*>(&Blds[1][bidx]);
            acc[s] = __builtin_amdgcn_mfma_f32_16x16x32_bf16(ah8, bh8, acc[s], 0, 0, 0);
            acc[s] = __builtin_amdgcn_mfma_f32_16x16x32_bf16(ah8, bl8, acc[s], 0, 0, 0);
            acc[s] = __builtin_amdgcn_mfma_f32_16x16x32_bf16(al8, bh8, acc[s], 0, 0, 0);
        }
    }

#pragma unroll
    for (int s = 0; s < 2; ++s) {
        int col = j0 + s * 16 + (l & 15);
#pragma unroll
        for (int r = 0; r < 4; ++r) {
            int b = m0 + w * 16 + ((l >> 4) << 2) + r;
            float pred = acc[s][r] + bout[col];
            float xv = x[(b * T_ + t) * D_ + col];
            float cv = (xv == 128.0f) ? pred : xv;
            int ci = b * D_ + col;
            split2(cv, curh[ci], curl[ci]);
            outPred[((size_t)b * (T_ - 1) + (t - 1)) * D_ + col] = pred;
        }
    }
}

extern "C" void kernel_launch(void* const* d_in, const int* in_sizes, int n_in,
                              void* d_out, int out_size, void* d_ws, size_t ws_size,
                              hipStream_t stream)
{
    const float* x  = (const float*)d_in[0];
    const float* k0 = (const float*)d_in[1];
    const float* r0 = (const float*)d_in[2];
    const float* b0 = (const float*)d_in[3];
    const float* k1 = (const float*)d_in[4];
    const float* r1 = (const float*)d_in[5];
    const float* b1 = (const float*)d_in[6];
    const float* W  = (const float*)d_in[7];
    const float* bo = (const float*)d_in[8];
    float* out = (float*)d_out;

    char* ws = (char*)d_ws;
    size_t off = 0;
    auto alloc = [&](size_t bytes) { void* p = ws + off; off += (bytes + 255) & ~255ull; return p; };
    __bf16* wB0Th = (__bf16*)alloc((size_t)2048 * 640 * 2);
    __bf16* wB0Tl = (__bf16*)alloc((size_t)2048 * 640 * 2);
    __bf16* wB1Th = (__bf16*)alloc((size_t)2048 * 1024 * 2);
    __bf16* wB1Tl = (__bf16*)alloc((size_t)2048 * 1024 * 2);
    __bf16* wWTh  = (__bf16*)alloc((size_t)128 * 512 * 2);
    __bf16* wWTl  = (__bf16*)alloc((size_t)128 * 512 * 2);
    __bf16* curh  = (__bf16*)alloc((size_t)B_ * D_ * 2);
    __bf16* curl  = (__bf16*)alloc((size_t)B_ * D_ * 2);
    __bf16* h0h[2] = { (__bf16*)alloc((size_t)B_ * H_ * 2), (__bf16*)alloc((size_t)B_ * H_ * 2) };
    __bf16* h0l[2] = { (__bf16*)alloc((size_t)B_ * H_ * 2), (__bf16*)alloc((size_t)B_ * H_ * 2) };
    __bf16* h1h[2] = { (__bf16*)alloc((size_t)B_ * H_ * 2), (__bf16*)alloc((size_t)B_ * H_ * 2) };
    __bf16* h1l[2] = { (__bf16*)alloc((size_t)B_ * H_ * 2), (__bf16*)alloc((size_t)B_ * H_ * 2) };
    float* c0 = (float*)alloc((size_t)B_ * H_ * 4);
    float* c1 = (float*)alloc((size_t)B_ * H_ * 4);

    k_convert<<<2048, 256, 0, stream>>>(k0, r0, k1, r1, W, wB0Th, wB0Tl, wB1Th, wB1Tl, wWTh, wWTl);
    k_init<<<1024, 256, 0, stream>>>(x, curh, curl,
                                     h0h[0], h0l[0], h0h[1], h0l[1],
                                     h1h[0], h1l[0], h1h[1], h1l[1], c0, c1);

    float* lastcell = out + (size_t)B_ * (T_ - 1) * D_;

    for (int t = 0; t < T_; ++t) {
        int cu = t & 1, pv = cu ^ 1;
        if (t > 0)
            k_pred<<<dim3(4, 8), 256, 0, stream>>>(h1h[pv], h1l[pv], wWTh, wWTl, bo, x, t,
                                                   curh, curl, out);
        k_layer<640, 128><<<dim3(32, 8), 512, 0, stream>>>(
            curh, curl, D_, h0h[pv], h0l[pv], H_, wB0Th, wB0Tl, b0, c0,
            h0h[cu], h0l[cu], nullptr);
        k_layer<1024, 512><<<dim3(32, 8), 512, 0, stream>>>(
            h0h[cu], h0l[cu], H_, h1h[pv], h1l[pv], H_, wB1Th, wB1Tl, b1, c1,
            h1h[cu], h1l[cu], (t == T_ - 1) ? lastcell : nullptr);
    }
}